// Round 10
// baseline (767.825 us; speedup 1.0000x reference)
//
#include <hip/hip_runtime.h>

#define N_NODES 100000
#define N_EDGES 1600000
#define N_GRAPHS 64
#define DIM 128
#define BN_EPS 1e-5f
#define EPAD (N_EDGES + 4 * N_NODES)

#define NB_DEG 6250   // 6250*256 = 1.6M edges
#define NB_EMB 6250   // 100k nodes * 16 thr
#define NB_SENT 977   // EPAD/(256*8)
#define NB_WPREP 192  // 3*128*128/256

typedef unsigned short ushort_t;
typedef unsigned int uint_t;
typedef __attribute__((ext_vector_type(8))) short bf16x8;
typedef __attribute__((ext_vector_type(4))) float f32x4;

__device__ __forceinline__ float bfl(uint_t u) {
    union { uint_t i; float f; } v; v.i = u << 16; return v.f;
}
__device__ __forceinline__ float bfh(uint_t u) {
    union { uint_t i; float f; } v; v.i = u & 0xffff0000u; return v.f;
}
__device__ __forceinline__ ushort_t f2bf(float f) {
    union { float f; uint_t i; } v; v.f = f;
    uint_t x = v.i;
    return (ushort_t)((x + 0x7fffu + ((x >> 16) & 1u)) >> 16);
}
__device__ __forceinline__ uint_t pack2(float lo, float hi) {
    return ((uint_t)f2bf(hi) << 16) | (uint_t)f2bf(lo);
}

// ---------------- zero scratch ----------------
__global__ void k_zero(int* __restrict__ p, int n) {
    int i = blockIdx.x * blockDim.x + threadIdx.x;
    if (i < n) p[i] = 0;
}

// ---------------- front mega-kernel: {degpos | embed | sentinel | wprep} ----------------
__global__ void k_front(const int* __restrict__ src, const int* __restrict__ dst,
                        int* __restrict__ dego, int* __restrict__ degi,
                        ushort_t* __restrict__ pos,
                        const int* __restrict__ tokens, const float* __restrict__ embed,
                        ushort_t* __restrict__ bufH, ushort_t* __restrict__ bufY,
                        int* __restrict__ esrc,
                        const float* __restrict__ w1, const float* __restrict__ w2,
                        const float* __restrict__ w3, ushort_t* __restrict__ wbt) {
    int b = blockIdx.x;
    int t = threadIdx.x;
    if (b < NB_DEG) {
        int e = b * 256 + t;
        if (e < N_EDGES) {
            atomicAdd(&dego[src[e]], 1);
            int p = atomicAdd(&degi[dst[e]], 1);
            pos[e] = (ushort_t)p;
        }
        return;
    }
    b -= NB_DEG;
    if (b < NB_EMB) {  // raw embedding gather (ns applied in aggbn)
        int gid = b * 256 + t;
        int node = gid >> 4, sub = gid & 15;
        const float* ep = embed + (size_t)tokens[node] * DIM + sub * 8;
        float4 a = *(const float4*)ep;
        float4 c = *(const float4*)(ep + 4);
        uint4 o;
        o.x = pack2(a.x, a.y); o.y = pack2(a.z, a.w);
        o.z = pack2(c.x, c.y); o.w = pack2(c.z, c.w);
        *(uint4*)(bufH + (size_t)node * DIM + sub * 8) = o;
        return;
    }
    b -= NB_EMB;
    if (b < NB_SENT) {  // esrc sentinel fill + zero sentinel feature rows
        int i0 = (b * 256 + t) * 8;
        int4 sv = make_int4(N_NODES, N_NODES, N_NODES, N_NODES);
        if (i0 + 8 <= EPAD) {
            *(int4*)(esrc + i0) = sv;
            *(int4*)(esrc + i0 + 4) = sv;
        } else {
            for (int i = i0; i < EPAD; ++i) esrc[i] = N_NODES;
        }
        if (b == 0 && t < 64) {
            ((uint_t*)(bufH + (size_t)N_NODES * DIM))[t] = 0u;
            ((uint_t*)(bufY + (size_t)N_NODES * DIM))[t] = 0u;
        }
        return;
    }
    b -= NB_SENT;
    {  // W fp32 [k][n] -> bf16 transposed [n][k]
        int i = b * 256 + t;
        int l = i >> 14;
        int idx = i & (DIM * DIM - 1);
        int n = idx >> 7, k = idx & (DIM - 1);
        const float* wsrc = (l == 0) ? w1 : (l == 1) ? w2 : w3;
        wbt[i] = f2bf(wsrc[k * DIM + n]);
    }
}

// ---------------- scan (rowptr from padded deg_in) + norms fused ----------------
#define SCAN_B 256
__global__ void k_scan1(const int* __restrict__ dego, const int* __restrict__ degi,
                        int* __restrict__ rowptr, int* __restrict__ partials,
                        float* __restrict__ ns, float* __restrict__ nd) {
    __shared__ int s[SCAN_B];
    int t = threadIdx.x;
    int i = blockIdx.x * SCAN_B + t;
    int d = (i < N_NODES) ? degi[i] : 0;
    int v = (d + 3) & ~3;  // pad rows to multiple of 4
    s[t] = v;
    __syncthreads();
    for (int off = 1; off < SCAN_B; off <<= 1) {
        int add = (t >= off) ? s[t - off] : 0;
        __syncthreads();
        s[t] += add;
        __syncthreads();
    }
    if (i < N_NODES) {
        rowptr[i + 1] = s[t];
        ns[i] = rsqrtf(fmaxf((float)dego[i], 1.0f));
        nd[i] = rsqrtf(fmaxf((float)d, 1.0f));
    }
    if (blockIdx.x == 0 && t == 0) ns[N_NODES] = 0.f;  // kills sentinel contributions
    if (t == SCAN_B - 1) partials[blockIdx.x] = s[t];
}

#define SCAN2_T 512
__global__ void k_scan2(int* __restrict__ partials, int* __restrict__ rowptr, int nb) {
    __shared__ int s[SCAN2_T];
    int t = threadIdx.x;
    int v = (t < nb) ? partials[t] : 0;
    s[t] = v;
    __syncthreads();
    for (int off = 1; off < SCAN2_T; off <<= 1) {
        int add = (t >= off) ? s[t - off] : 0;
        __syncthreads();
        s[t] += add;
        __syncthreads();
    }
    if (t < nb) partials[t] = s[t] - v;  // exclusive
    if (t == 0) rowptr[0] = 0;
}

__global__ void k_scan3(const int* __restrict__ partials, int* __restrict__ rowptr) {
    int i = blockIdx.x * SCAN_B + threadIdx.x;
    if (i < N_NODES) rowptr[i + 1] += partials[blockIdx.x];
}

// ---------------- CSR scatter (atomic-free) ----------------
__global__ void k_scatter(const int* __restrict__ src, const int* __restrict__ dst,
                          const int* __restrict__ rowptr, const ushort_t* __restrict__ pos,
                          int* __restrict__ esrc) {
    int e = blockIdx.x * blockDim.x + threadIdx.x;
    if (e < N_EDGES) {
        int d = dst[e];
        esrc[rowptr[d] + (int)pos[e]] = src[e];
    }
}

// ---------------- aggregation, half-wave edge pairing + fused BN+relu+ns ----------------
// One wave per node. Lanes 0-31 process even edges, 32-63 odd edges; each lane
// covers 4 cols via uint2 loads, so one row-load instruction serves 2 edges.
template <int DOBN>
__global__ __launch_bounds__(256) void k_aggbn(const ushort_t* __restrict__ hs,
        const int* __restrict__ rowptr, const int* __restrict__ esrc,
        const float* __restrict__ ns, const float* __restrict__ nd,
        const float* __restrict__ bnsum, const float* __restrict__ bnsq,
        const float* __restrict__ g, const float* __restrict__ be,
        ushort_t* __restrict__ agg) {
    __shared__ float sa[DIM], sc[DIM];
    int tid = threadIdx.x;
    if (DOBN) {
        if (tid < DIM) {
            float mu = bnsum[tid] * (1.0f / N_NODES);
            float var = bnsq[tid] * (1.0f / N_NODES) - mu * mu;
            float rstd = rsqrtf(var + BN_EPS);
            float a = g[tid] * rstd;
            sa[tid] = a;
            sc[tid] = be[tid] - mu * a;
        }
        __syncthreads();
    }
    int wid = (blockIdx.x * 256 + tid) >> 6;
    if (wid >= N_NODES) return;
    int lane = tid & 63;
    int half = lane >> 5;
    int l32 = lane & 31;
    int off = l32 * 4;  // 4 cols per lane
    float a0 = 0.f, a1 = 0.f, a2 = 0.f, a3 = 0.f;
    float c0 = 0.f, c1 = 0.f, c2 = 0.f, c3 = 0.f;
    if (DOBN) {
        a0 = sa[off]; a1 = sa[off + 1]; a2 = sa[off + 2]; a3 = sa[off + 3];
        c0 = sc[off]; c1 = sc[off + 1]; c2 = sc[off + 2]; c3 = sc[off + 3];
    }
    int beg = rowptr[wid], end = rowptr[wid + 1];  // multiple of 4, beg 4-aligned
    float x0 = 0.f, x1 = 0.f, x2 = 0.f, x3 = 0.f;  // chain A
    float y0 = 0.f, y1 = 0.f, y2 = 0.f, y3 = 0.f;  // chain B

#define AGG_ONE(U, N, X0, X1, X2, X3)                                          \
    {                                                                          \
        float v0 = bfl(U.x), v1 = bfh(U.x), v2 = bfl(U.y), v3 = bfh(U.y);      \
        if (DOBN) {                                                            \
            v0 = fmaxf(fmaf(v0, a0, c0), 0.f);                                 \
            v1 = fmaxf(fmaf(v1, a1, c1), 0.f);                                 \
            v2 = fmaxf(fmaf(v2, a2, c2), 0.f);                                 \
            v3 = fmaxf(fmaf(v3, a3, c3), 0.f);                                 \
        }                                                                      \
        X0 = fmaf(v0, N, X0); X1 = fmaf(v1, N, X1);                            \
        X2 = fmaf(v2, N, X2); X3 = fmaf(v3, N, X3);                            \
    }

    int e = beg;
    for (; e + 8 <= end; e += 8) {
        int4 i0 = *(const int4*)(esrc + e);
        int4 i1 = *(const int4*)(esrc + e + 4);
        int s0 = half ? i0.y : i0.x;
        int s1 = half ? i0.w : i0.z;
        int s2 = half ? i1.y : i1.x;
        int s3 = half ? i1.w : i1.z;
        uint2 u0 = *(const uint2*)(hs + (size_t)s0 * DIM + off);
        uint2 u1 = *(const uint2*)(hs + (size_t)s1 * DIM + off);
        uint2 u2 = *(const uint2*)(hs + (size_t)s2 * DIM + off);
        uint2 u3 = *(const uint2*)(hs + (size_t)s3 * DIM + off);
        float n0 = ns[s0], n1 = ns[s1], n2 = ns[s2], n3 = ns[s3];
        AGG_ONE(u0, n0, x0, x1, x2, x3);
        AGG_ONE(u1, n1, y0, y1, y2, y3);
        AGG_ONE(u2, n2, x0, x1, x2, x3);
        AGG_ONE(u3, n3, y0, y1, y2, y3);
    }
    if (e < end) {  // remaining 4
        int4 i0 = *(const int4*)(esrc + e);
        int s0 = half ? i0.y : i0.x;
        int s1 = half ? i0.w : i0.z;
        uint2 u0 = *(const uint2*)(hs + (size_t)s0 * DIM + off);
        uint2 u1 = *(const uint2*)(hs + (size_t)s1 * DIM + off);
        float n0 = ns[s0], n1 = ns[s1];
        AGG_ONE(u0, n0, x0, x1, x2, x3);
        AGG_ONE(u1, n1, y0, y1, y2, y3);
    }
#undef AGG_ONE

    float t0 = x0 + y0, t1 = x1 + y1, t2 = x2 + y2, t3 = x3 + y3;
    t0 += __shfl_xor(t0, 32);
    t1 += __shfl_xor(t1, 32);
    t2 += __shfl_xor(t2, 32);
    t3 += __shfl_xor(t3, 32);
    if (half == 0) {
        float n = nd[wid];
        uint2 o;
        o.x = pack2(t0 * n, t1 * n);
        o.y = pack2(t2 * n, t3 * n);
        *(uint2*)(agg + (size_t)wid * DIM + off) = o;
    }
}

// ---------------- MFMA GEMM + fused BN stats, B staged in LDS fragment-order ----------------
__global__ __launch_bounds__(256) void k_gemm(const ushort_t* __restrict__ x,
                                              const ushort_t* __restrict__ wbt,
                                              const float* __restrict__ bias,
                                              ushort_t* __restrict__ y,
                                              float* __restrict__ bnsum,
                                              float* __restrict__ bnsq) {
    __shared__ ushort_t bs[2048 * 8];
    __shared__ float csum[DIM];
    __shared__ float csq[DIM];
#pragma unroll
    for (int i = 0; i < 8; ++i) {
        int f = threadIdx.x + i * 256;
        int fm16 = f & 15;
        int fquad = (f >> 4) & 3;
        int fnb = (f >> 6) & 7;
        int fk0b = f >> 9;
        int ncol = fnb * 16 + fm16;
        *(uint4*)&bs[f * 8] = *(const uint4*)(wbt + (size_t)ncol * DIM + fk0b * 32 + fquad * 8);
    }
    if (threadIdx.x < DIM) { csum[threadIdx.x] = 0.f; csq[threadIdx.x] = 0.f; }
    __syncthreads();

    int wave = threadIdx.x >> 6;
    int lane = threadIdx.x & 63;
    int m16 = lane & 15;
    int quad = lane >> 4;
    int row0 = blockIdx.x * 64 + wave * 16;

    f32x4 acc[8];
#pragma unroll
    for (int nb = 0; nb < 8; ++nb) acc[nb] = (f32x4)(0.f);

    int arow = row0 + m16;
    bool rowok = arow < N_NODES;
    const ushort_t* xp = x + (size_t)arow * DIM + quad * 8;

#pragma unroll
    for (int k0b = 0; k0b < 4; ++k0b) {
        bf16x8 af;
        if (rowok) af = *(const bf16x8*)(xp + k0b * 32);
        else af = (bf16x8)(short)0;
#pragma unroll
        for (int nb = 0; nb < 8; ++nb) {
            bf16x8 bfg = *(const bf16x8*)&bs[(((k0b * 8 + nb) << 6) + lane) * 8];
            acc[nb] = __builtin_amdgcn_mfma_f32_16x16x32_bf16(af, bfg, acc[nb], 0, 0, 0);
        }
    }

#pragma unroll
    for (int nb = 0; nb < 8; ++nb) {
        int col = nb * 16 + m16;
        float bcol = bias[col];
        float ps = 0.f, pq = 0.f;
#pragma unroll
        for (int reg = 0; reg < 4; ++reg) {
            int r = row0 + quad * 4 + reg;
            if (r < N_NODES) {
                float v = acc[nb][reg] + bcol;
                ps += v; pq += v * v;
                y[(size_t)r * DIM + col] = f2bf(v);
            }
        }
        atomicAdd(&csum[col], ps);
        atomicAdd(&csq[col], pq);
    }
    __syncthreads();
    if (threadIdx.x < DIM) {
        atomicAdd(&bnsum[threadIdx.x], csum[threadIdx.x]);
        atomicAdd(&bnsq[threadIdx.x], csq[threadIdx.x]);
    }
}

// ---------------- pooling: fused layer-3 BN fold+apply + graph counts ----------------
#define POOL_NODES 256
__global__ void k_pool(const ushort_t* __restrict__ yin, const int* __restrict__ gids,
                       const float* __restrict__ bnsum, const float* __restrict__ bnsq,
                       const float* __restrict__ g, const float* __restrict__ be,
                       float* __restrict__ pool, int* __restrict__ cnt) {
    __shared__ int h[N_GRAPHS];
    int col = threadIdx.x;  // 128
    float mu = bnsum[col] * (1.0f / N_NODES);
    float var = bnsq[col] * (1.0f / N_NODES) - mu * mu;
    float rstd = rsqrtf(var + BN_EPS);
    float a = g[col] * rstd;
    float c = be[col] - mu * a;
    if (col < N_GRAPHS) h[col] = 0;
    __syncthreads();
    int base = blockIdx.x * POOL_NODES;
    int end = min(base + POOL_NODES, N_NODES);
    for (int n = base + col; n < end; n += 128) atomicAdd(&h[gids[n]], 1);
    __syncthreads();
    if (col < N_GRAPHS && h[col]) atomicAdd(&cnt[col], h[col]);
    float acc = 0.f;
    int cur = gids[base];
    for (int n = base; n < end; ++n) {
        int gg = gids[n];
        if (gg != cur) {
            atomicAdd(&pool[(size_t)cur * DIM + col], acc);
            acc = 0.f;
            cur = gg;
        }
        uint_t u = *(const uint_t*)(yin + (size_t)n * DIM + (col & ~1));
        float v = (col & 1) ? bfh(u) : bfl(u);
        acc += fmaxf(fmaf(v, a, c), 0.f);
    }
    atomicAdd(&pool[(size_t)cur * DIM + col], acc);
}

// ---------------- final FC (one block per graph) ----------------
__global__ void k_final(const float* __restrict__ pool, const int* __restrict__ cnt,
                        const float* __restrict__ fcW1, const float* __restrict__ fcb1,
                        const float* __restrict__ fcW2, const float* __restrict__ fcb2,
                        float* __restrict__ out) {
    __shared__ float hg[DIM];
    __shared__ float z[64];
    int g = blockIdx.x;
    int t = threadIdx.x;  // 128
    float cf = fmaxf((float)cnt[g], 1.0f);
    hg[t] = pool[(size_t)g * DIM + t] / cf;
    __syncthreads();
    if (t < 64) {
        float acc = fcb1[t];
        for (int k = 0; k < DIM; ++k)
            acc += hg[k] * fcW1[k * 64 + t];
        z[t] = fmaxf(acc, 0.f);
    }
    __syncthreads();
    if (t < 2) {
        float acc = fcb2[t];
        for (int k = 0; k < 64; ++k)
            acc += z[k] * fcW2[k * 2 + t];
        out[g * 2 + t] = acc;
    }
}

extern "C" void kernel_launch(void* const* d_in, const int* in_sizes, int n_in,
                              void* d_out, int out_size, void* d_ws, size_t ws_size,
                              hipStream_t stream) {
    const int* tokens = (const int*)d_in[0];
    const int* src = (const int*)d_in[1];
    const int* dst = (const int*)d_in[2];
    const int* gids = (const int*)d_in[3];
    const float* embed = (const float*)d_in[4];
    const float* W1 = (const float*)d_in[5];
    const float* b1 = (const float*)d_in[6];
    const float* g1 = (const float*)d_in[7];
    const float* be1 = (const float*)d_in[8];
    const float* W2 = (const float*)d_in[9];
    const float* b2 = (const float*)d_in[10];
    const float* g2 = (const float*)d_in[11];
    const float* be2 = (const float*)d_in[12];
    const float* W3 = (const float*)d_in[13];
    const float* b3 = (const float*)d_in[14];
    const float* g3 = (const float*)d_in[15];
    const float* be3 = (const float*)d_in[16];
    const float* fcW1 = (const float*)d_in[17];
    const float* fcb1 = (const float*)d_in[18];
    const float* fcW2 = (const float*)d_in[19];
    const float* fcb2 = (const float*)d_in[20];
    float* out = (float*)d_out;

    char* w = (char*)d_ws;
    auto alloc = [&](size_t bytes) {
        void* p = (void*)w;
        w += (bytes + 255) & ~(size_t)255;
        return p;
    };
    ushort_t* bufH = (ushort_t*)alloc((size_t)(N_NODES + 1) * DIM * 2);  // embed out (raw)
    ushort_t* bufY = (ushort_t*)alloc((size_t)(N_NODES + 1) * DIM * 2);  // gemm out (pre-BN)
    ushort_t* bufAgg = (ushort_t*)alloc((size_t)N_NODES * DIM * 2);      // aggregate out
    int* esrc = (int*)alloc((size_t)EPAD * 4);
    ushort_t* pos = (ushort_t*)alloc((size_t)N_EDGES * 2);
    int* rowptr = (int*)alloc((size_t)(N_NODES + 1) * 4);
    float* ns = (float*)alloc((size_t)(N_NODES + 1) * 4);
    float* nd = (float*)alloc((size_t)N_NODES * 4);
    int* partials = (int*)alloc(1024 * 4);
    ushort_t* wbt = (ushort_t*)alloc(3 * DIM * DIM * 2);
    // zeroed region (contiguous)
    char* zstart = w;
    int* dego = (int*)alloc((size_t)N_NODES * 4);
    int* degi = (int*)alloc((size_t)N_NODES * 4);
    float* bnsum = (float*)alloc(3 * DIM * 4);
    float* bnsq = (float*)alloc(3 * DIM * 4);
    float* pool = (float*)alloc((size_t)N_GRAPHS * DIM * 4);
    int* cnt = (int*)alloc((size_t)N_GRAPHS * 4);
    int zwords = (int)((size_t)(w - zstart) / 4);

    int nb_e = (N_EDGES + 255) / 256;
    int nb_scan = (N_NODES + SCAN_B - 1) / SCAN_B;

    k_zero<<<(zwords + 255) / 256, 256, 0, stream>>>((int*)zstart, zwords);
    k_front<<<NB_DEG + NB_EMB + NB_SENT + NB_WPREP, 256, 0, stream>>>(
        src, dst, dego, degi, pos, tokens, embed, bufH, bufY, esrc, W1, W2, W3, wbt);
    k_scan1<<<nb_scan, SCAN_B, 0, stream>>>(dego, degi, rowptr, partials, ns, nd);
    k_scan2<<<1, SCAN2_T, 0, stream>>>(partials, rowptr, nb_scan);
    k_scan3<<<nb_scan, SCAN_B, 0, stream>>>(partials, rowptr);
    k_scatter<<<nb_e, 256, 0, stream>>>(src, dst, rowptr, pos, esrc);

    const float* bias_l[3] = {b1, b2, b3};
    const float* g_l[3] = {g1, g2, g3};
    const float* be_l[3] = {be1, be2, be3};
    int nb_agg = (N_NODES * 64 + 255) / 256;
    int nb_gemm = (N_NODES + 63) / 64;

    for (int l = 0; l < 3; ++l) {
        const ushort_t* hs_in = (l == 0) ? bufH : bufY;
        if (l == 0)
            k_aggbn<0><<<nb_agg, 256, 0, stream>>>(hs_in, rowptr, esrc, ns, nd,
                                                   nullptr, nullptr, nullptr, nullptr, bufAgg);
        else
            k_aggbn<1><<<nb_agg, 256, 0, stream>>>(hs_in, rowptr, esrc, ns, nd,
                                                   bnsum + (l - 1) * DIM, bnsq + (l - 1) * DIM,
                                                   g_l[l - 1], be_l[l - 1], bufAgg);
        k_gemm<<<nb_gemm, 256, 0, stream>>>(bufAgg, wbt + (size_t)l * DIM * DIM, bias_l[l],
                                            bufY, bnsum + l * DIM, bnsq + l * DIM);
    }

    k_pool<<<(N_NODES + POOL_NODES - 1) / POOL_NODES, DIM, 0, stream>>>(
        bufY, gids, bnsum + 2 * DIM, bnsq + 2 * DIM, g3, be3, pool, cnt);
    k_final<<<N_GRAPHS, DIM, 0, stream>>>(pool, cnt, fcW1, fcb1, fcW2, fcb2, out);
}